// Round 10
// baseline (26.402 us; speedup 1.0000x reference)
//
#include <hip/hip_runtime.h>

// LengthRegulator: B=32, L=256, H=384, T(MAX_WAVE)=2048
// out0: (B, H, T) float32 = gathered^T ; out1: (B, T) float32 mask
constexpr int Lc = 256;
constexpr int Hc = 384;
constexpr int Tc = 2048;
constexpr int Bc = 32;
constexpr int H_TILE = 16;   // grid (24, 32) = 768 blocks x 512 threads

typedef float floatx4 __attribute__((ext_vector_type(4)));

__global__ __launch_bounds__(512) void lr_fused_kernel(
    const float* __restrict__ enc,   // (B, L, H)
    const int*   __restrict__ dur,   // (B, L)
    float*       __restrict__ out,   // (B, H, T)
    float*       __restrict__ mask)  // (B, T)
{
    const int tid  = threadIdx.x;     // 0..511
    const int lane = tid & 63;
    const int wv   = tid >> 6;        // wave 0..7
    const int b    = blockIdx.y;
    const int h0   = blockIdx.x * H_TILE;

    __shared__ unsigned short s_row[Tc];   // 4 KB: t -> row index
    __shared__ int            s_wtot[8];

    // ---- 1) duration load (threads 0..255) + pre-fill s_row with 255 ------
    int d = 0;
    if (tid < Lc) d = dur[b * Lc + tid];
    {
        uint2 f; f.x = 0x00FF00FFu; f.y = 0x00FF00FFu;
        *reinterpret_cast<uint2*>(s_row + tid * 4) = f;   // 4 ushorts/thread
    }

    // ---- 2) barrier-free wave scan of durations (waves 4..7 scan zeros) ----
    int s = d;
#pragma unroll
    for (int off = 1; off < 64; off <<= 1) {
        int t = __shfl_up(s, off);
        if (lane >= off) s += t;
    }
    if (lane == 63) s_wtot[wv] = s;

    __syncthreads();  // barrier #1 (prefill + wave totals visible)

    // ---- 3) cross-wave offsets + scatter row indices -----------------------
    int pre = 0, total = 0;
#pragma unroll
    for (int w = 0; w < 4; ++w) {     // only waves 0..3 hold durations
        int t = s_wtot[w];
        total += t;
        if (w < wv) pre += t;
    }
    if (tid < Lc) {
        const int csum_i = s + pre;          // inclusive csum at position tid
        const int excl   = csum_i - d;       // exclusive prefix
        int hiw = csum_i; if (hiw > Tc) hiw = Tc;
        for (int t = excl; t < hiw; ++t) s_row[t] = (unsigned short)tid;
    }

    __syncthreads();  // barrier #2

    // ---- 4) gather DIRECT from global (L2-hot, 16x reuse) + store out ------
    // A/B vs round 9: REGULAR stores (no nontemporal). out fits in 256MB L3;
    // regular stores complete at L3, NT forced the HBM drain into kernel time.
    const int tbase = tid * 4;               // whole T covered by one block
    ushort4 iv = *reinterpret_cast<const ushort4*>(s_row + tbase);

    const float* encb = enc + (size_t)b * (Lc * Hc) + h0;
    const float* rp0 = encb + (size_t)iv.x * Hc;
    const float* rp1 = encb + (size_t)iv.y * Hc;
    const float* rp2 = encb + (size_t)iv.z * Hc;
    const float* rp3 = encb + (size_t)iv.w * Hc;

    const float m0 = (tbase + 0 < total) ? 1.0f : 0.0f;
    const float m1 = (tbase + 1 < total) ? 1.0f : 0.0f;
    const float m2 = (tbase + 2 < total) ? 1.0f : 0.0f;
    const float m3 = (tbase + 3 < total) ? 1.0f : 0.0f;

    float* outb = out + (size_t)b * (Hc * Tc) + (size_t)h0 * Tc + tbase;
#pragma unroll
    for (int hh0 = 0; hh0 < H_TILE; hh0 += 4) {
        // 4 x global b128 loads: row of each t, cols hh0..hh0+3 (16B aligned)
        floatx4 a0 = *reinterpret_cast<const floatx4*>(rp0 + hh0);
        floatx4 a1 = *reinterpret_cast<const floatx4*>(rp1 + hh0);
        floatx4 a2 = *reinterpret_cast<const floatx4*>(rp2 + hh0);
        floatx4 a3 = *reinterpret_cast<const floatx4*>(rp3 + hh0);
#pragma unroll
        for (int j = 0; j < 4; ++j) {
            floatx4 v;
            v.x = a0[j] * m0;
            v.y = a1[j] * m1;
            v.z = a2[j] * m2;
            v.w = a3[j] * m3;
            *reinterpret_cast<floatx4*>(outb + (size_t)(hh0 + j) * Tc) = v;
        }
    }

    // ---- 5) mask (one h-tile writes it) ------------------------------------
    if (blockIdx.x == 0) {
        floatx4 m; m.x = m0; m.y = m1; m.z = m2; m.w = m3;
        *reinterpret_cast<floatx4*>(mask + (size_t)b * Tc + tbase) = m;
    }
}

extern "C" void kernel_launch(void* const* d_in, const int* in_sizes, int n_in,
                              void* d_out, int out_size, void* d_ws, size_t ws_size,
                              hipStream_t stream) {
    const float* enc = (const float*)d_in[0];   // (32, 256, 384) f32
    const int*   dur = (const int*)d_in[1];     // (32, 256) i32

    float* out  = (float*)d_out;                      // (32, 384, 2048)
    float* mask = out + (size_t)Bc * Hc * Tc;         // (32, 2048)

    dim3 grid(Hc / H_TILE, Bc);   // (24, 32) = 768 blocks of 512 threads
    dim3 block(512);
    lr_fused_kernel<<<grid, block, 0, stream>>>(enc, dur, out, mask);
}

// Round 11
// 24.401 us; speedup vs baseline: 1.0820x; 1.0820x over previous
//
#include <hip/hip_runtime.h>

// LengthRegulator: B=32, L=256, H=384, T(MAX_WAVE)=2048
// out0: (B, H, T) float32 = gathered^T ; out1: (B, T) float32 mask
constexpr int Lc = 256;
constexpr int Hc = 384;
constexpr int Tc = 2048;
constexpr int Bc = 32;
constexpr int H_TILE = 16;   // grid (24, 32) = 768 blocks x 512 threads
constexpr int PADW = 17;     // LDS row stride; 17 coprime 32 -> conflict-free scalar gather

typedef float floatx4 __attribute__((ext_vector_type(4)));

__global__ __launch_bounds__(512) void lr_fused_kernel(
    const float* __restrict__ enc,   // (B, L, H)
    const int*   __restrict__ dur,   // (B, L)
    float*       __restrict__ out,   // (B, H, T)
    float*       __restrict__ mask)  // (B, T)
{
    const int tid  = threadIdx.x;     // 0..511
    const int lane = tid & 63;
    const int wv   = tid >> 6;        // wave 0..7
    const int b    = blockIdx.y;
    const int h0   = blockIdx.x * H_TILE;

    __shared__ float          s_enc[Lc * PADW];  // 17 KB
    __shared__ unsigned short s_row[Tc];         // 4 KB
    __shared__ int            s_wtot[8];

    // ---- 1) issue enc-tile staging loads FIRST ------------------------------
    const float* encb = enc + (size_t)b * (Lc * Hc) + h0;
    const int r  = tid >> 2;          // 0..127
    const int c4 = (tid & 3) * 4;     // 0,4,8,12
    floatx4 st0 = *reinterpret_cast<const floatx4*>(encb + (size_t)r * Hc + c4);
    floatx4 st1 = *reinterpret_cast<const floatx4*>(encb + (size_t)(r + 128) * Hc + c4);

    // ---- 2) duration load + pre-fill s_row with 255 -------------------------
    int d = 0;
    if (tid < Lc) d = dur[b * Lc + tid];
    {
        uint2 f; f.x = 0x00FF00FFu; f.y = 0x00FF00FFu;
        *reinterpret_cast<uint2*>(s_row + tid * 4) = f;   // 4 ushorts/thread
    }

    // ---- 3) barrier-free wave scan of durations -----------------------------
    int s = d;
#pragma unroll
    for (int off = 1; off < 64; off <<= 1) {
        int t = __shfl_up(s, off);
        if (lane >= off) s += t;
    }
    if (lane == 63) s_wtot[wv] = s;

    // land staged tile into LDS (scalar writes; PADW=17 rows not 16B-aligned)
    {
        float* d0 = s_enc + r * PADW + c4;
        d0[0] = st0.x; d0[1] = st0.y; d0[2] = st0.z; d0[3] = st0.w;
        float* d1 = s_enc + (r + 128) * PADW + c4;
        d1[0] = st1.x; d1[1] = st1.y; d1[2] = st1.z; d1[3] = st1.w;
    }

    __syncthreads();  // barrier #1

    // ---- 4) cross-wave offsets + scatter row indices ------------------------
    int pre = 0, total = 0;
#pragma unroll
    for (int w = 0; w < 4; ++w) {     // only waves 0..3 hold durations
        int t = s_wtot[w];
        total += t;
        if (w < wv) pre += t;
    }
    if (tid < Lc) {
        const int csum_i = s + pre;
        const int excl   = csum_i - d;
        int hiw = csum_i; if (hiw > Tc) hiw = Tc;
        for (int t = excl; t < hiw; ++t) s_row[t] = (unsigned short)tid;
    }

    __syncthreads();  // barrier #2

    // ---- 5) preload this lane's row indices for all 8 t-chunks --------------
    ushort4 ivv[8];
#pragma unroll
    for (int it = 0; it < 8; ++it)
        ivv[it] = *reinterpret_cast<const ushort4*>(s_row + it * 256 + lane * 4);

    // ---- 6) WAVE-LINEAR stores: wave wv owns h = wv and wv+8 ----------------
    // per (wave,h): 8 consecutive 1KB stores -> 8KB sequential DRAM stream.
    float* outB = out + (size_t)b * (Hc * Tc) + (size_t)h0 * Tc;
#pragma unroll
    for (int hp = 0; hp < 2; ++hp) {
        const int h = wv + hp * 8;                     // wave-uniform
        float* outrow = outB + (size_t)h * Tc;
#pragma unroll
        for (int it = 0; it < 8; ++it) {
            const int t0 = it * 256 + lane * 4;
            floatx4 v;
            v.x = s_enc[(int)ivv[it].x * PADW + h] * ((t0 + 0 < total) ? 1.0f : 0.0f);
            v.y = s_enc[(int)ivv[it].y * PADW + h] * ((t0 + 1 < total) ? 1.0f : 0.0f);
            v.z = s_enc[(int)ivv[it].z * PADW + h] * ((t0 + 2 < total) ? 1.0f : 0.0f);
            v.w = s_enc[(int)ivv[it].w * PADW + h] * ((t0 + 3 < total) ? 1.0f : 0.0f);
            __builtin_nontemporal_store(v, reinterpret_cast<floatx4*>(outrow + t0));
        }
    }

    // ---- 7) mask (one h-tile writes it) -------------------------------------
    if (blockIdx.x == 0) {
        const int tb = tid * 4;
        floatx4 m;
        m.x = (tb + 0 < total) ? 1.0f : 0.0f;
        m.y = (tb + 1 < total) ? 1.0f : 0.0f;
        m.z = (tb + 2 < total) ? 1.0f : 0.0f;
        m.w = (tb + 3 < total) ? 1.0f : 0.0f;
        __builtin_nontemporal_store(
            m, reinterpret_cast<floatx4*>(mask + (size_t)b * Tc + tb));
    }
}

extern "C" void kernel_launch(void* const* d_in, const int* in_sizes, int n_in,
                              void* d_out, int out_size, void* d_ws, size_t ws_size,
                              hipStream_t stream) {
    const float* enc = (const float*)d_in[0];   // (32, 256, 384) f32
    const int*   dur = (const int*)d_in[1];     // (32, 256) i32

    float* out  = (float*)d_out;                      // (32, 384, 2048)
    float* mask = out + (size_t)Bc * Hc * Tc;         // (32, 2048)

    dim3 grid(Hc / H_TILE, Bc);   // (24, 32) = 768 blocks of 512 threads
    dim3 block(512);
    lr_fused_kernel<<<grid, block, 0, stream>>>(enc, dur, out, mask);
}